// Round 3
// baseline (479.937 us; speedup 1.0000x reference)
//
#include <hip/hip_runtime.h>

// MS-SSIM, B=16 C=3 H=W=512, f32, win=11 sigma=1.5, 5 levels.
// Round 3 structure: per level, one fused kernel:
//   phase 1: cooperative stage of input x/y tile into LDS (only LDS use)
//   phase 2: per-thread column walk: horizontal 11-tap blur of
//            {x,y,xx,yy,xy} into an 11-deep REGISTER ring, vertical 11-tap
//            blur from the ring, ssim/cs, accumulate. No second LDS pass.
// acc layout in ws: [level][48][2] floats (ssim_sum, cs_sum), then pyramid.

#define TW 32               // output tile width (one column per thread)
#define TH 64               // output tile height
#define RPT 8               // output rows per thread (TH / 8 row-groups)
#define HALO 10
#define IW (TW + HALO)      // 42 input cols
#define IH (TH + HALO)      // 74 input rows
#define ISTR (IW + 1)       // 43: pad; halves-of-wave land on disjoint banks

// Gaussian window, size 11, sigma 1.5, normalized (computed in double, rounded).
__device__ __constant__ float G11[11] = {
    0.001028380f, 0.007598758f, 0.036000773f, 0.109360680f, 0.213005529f,
    0.266011731f,
    0.213005529f, 0.109360680f, 0.036000773f, 0.007598758f, 0.001028380f
};

__device__ __forceinline__ float fastdiv(float a, float b) {
    float r = __builtin_amdgcn_rcpf(b);
    r = r * __builtin_fmaf(-b, r, 2.0f);   // one Newton step -> ~f32-exact
    return a * r;
}

// horizontal 11-tap blur of {x,y,xx,yy,xy} at (ROW, tx) -> ring slot SLOT
#define HBLUR(ROW, SLOT) do {                                              \
    const float* px_ = &sx[(ROW) * ISTR + tx];                             \
    const float* py_ = &sy[(ROW) * ISTR + tx];                             \
    float bx_ = 0.f, by_ = 0.f, bxx_ = 0.f, byy_ = 0.f, bxy_ = 0.f;        \
    _Pragma("unroll")                                                      \
    for (int t_ = 0; t_ < 11; ++t_) {                                      \
        float w_  = G11[t_];                                               \
        float xv_ = px_[t_];                                               \
        float yv_ = py_[t_];                                               \
        bx_  += w_ * xv_;                                                  \
        by_  += w_ * yv_;                                                  \
        bxx_ += w_ * xv_ * xv_;                                            \
        byy_ += w_ * yv_ * yv_;                                            \
        bxy_ += w_ * xv_ * yv_;                                            \
    }                                                                      \
    rbx[SLOT] = bx_; rby[SLOT] = by_; rbxx[SLOT] = bxx_;                   \
    rbyy[SLOT] = byy_; rbxy[SLOT] = bxy_;                                  \
} while (0)

__global__ __launch_bounds__(256, 5)
void ssim_level_kernel(const float* __restrict__ X, const float* __restrict__ Y,
                       int H, int W, int Hs, int Ws, float* __restrict__ acc)
{
    __shared__ float sx[IH * ISTR];
    __shared__ float sy[IH * ISTR];
    __shared__ float red[2][4];

    const int bc  = blockIdx.z;
    const int ox  = blockIdx.x * TW;
    const int oy  = blockIdx.y * TH;
    const int tid = threadIdx.x;
    const size_t base = (size_t)bc * H * W;

    // ---- stage 74x42 input tile of X and Y (row-clamped; clamped texels only
    // feed masked-out outputs) ----
    for (int idx = tid; idx < IH * IW; idx += 256) {
        int r = idx / IW;
        int c = idx - r * IW;
        int gr = oy + r; if (gr > H - 1) gr = H - 1;
        int gc = ox + c; if (gc > W - 1) gc = W - 1;
        size_t g = base + (size_t)gr * W + gc;
        sx[r * ISTR + c] = X[g];
        sy[r * ISTR + c] = Y[g];
    }
    __syncthreads();

    const int tx = tid & 31;        // column within tile
    const int ty = tid >> 5;        // row-group 0..7
    const int g0 = ty * RPT;        // first output row of this thread

    // ---- register ring: 11 rows x 5 horizontally-blurred quantities ----
    float rbx[11], rby[11], rbxx[11], rbyy[11], rbxy[11];

#pragma unroll
    for (int t0 = 0; t0 < 10; ++t0) {
        HBLUR(g0 + t0, t0);
    }

    const bool colok = (ox + tx) < Ws;
    float ssum = 0.f, csum = 0.f;

#pragma unroll
    for (int i = 0; i < RPT; ++i) {
        HBLUR(g0 + 10 + i, (10 + i) % 11);

        float m1 = 0.f, m2 = 0.f, qxx = 0.f, qyy = 0.f, qxy = 0.f;
#pragma unroll
        for (int t = 0; t < 11; ++t) {
            const int s = (i + t) % 11;       // compile-time after unroll
            float w = G11[t];
            m1  += w * rbx[s];
            m2  += w * rby[s];
            qxx += w * rbxx[s];
            qyy += w * rbyy[s];
            qxy += w * rbxy[s];
        }
        if (colok && (oy + g0 + i) < Hs) {
            const float C1 = 0.0001f, C2 = 0.0009f;
            float mu1s = m1 * m1, mu2s = m2 * m2, mu12 = m1 * m2;
            float s1  = qxx - mu1s;
            float s2  = qyy - mu2s;
            float s12 = qxy - mu12;
            float cs  = fastdiv(2.f * s12 + C2, s1 + s2 + C2);
            float ss  = fastdiv((2.f * mu12 + C1) * cs, mu1s + mu2s + C1);
            ssum += ss;
            csum += cs;
        }
    }

    // ---- block reduction: wave64 shfl, then cross-wave via LDS ----
#pragma unroll
    for (int off = 32; off; off >>= 1) {
        ssum += __shfl_down(ssum, off);
        csum += __shfl_down(csum, off);
    }
    if ((tid & 63) == 0) {
        red[0][tid >> 6] = ssum;
        red[1][tid >> 6] = csum;
    }
    __syncthreads();
    if (tid == 0) {
        float s = red[0][0] + red[0][1] + red[0][2] + red[0][3];
        float c = red[1][0] + red[1][1] + red[1][2] + red[1][3];
        atomicAdd(&acc[bc * 2 + 0], s);
        atomicAdd(&acc[bc * 2 + 1], c);
    }
}

// 2x2 avg-pool, stride 2, no padding (all level sizes even). Both tensors in one pass.
__launch_bounds__(256)
__global__ void down_kernel(const float* __restrict__ Xi, const float* __restrict__ Yi,
                            float* __restrict__ Xo, float* __restrict__ Yo,
                            int Ho, int Wo, int n)
{
    int idx = blockIdx.x * 256 + threadIdx.x;
    if (idx >= n) return;
    int w  = idx % Wo;
    int t  = idx / Wo;
    int h  = t % Ho;
    int bc = t / Ho;
    int W  = Wo * 2;
    size_t ib = (size_t)bc * (4 * Ho * Wo) + (size_t)(2 * h) * W + 2 * w;
    float2 a0 = *reinterpret_cast<const float2*>(Xi + ib);
    float2 a1 = *reinterpret_cast<const float2*>(Xi + ib + W);
    Xo[idx] = 0.25f * (a0.x + a0.y + a1.x + a1.y);
    float2 b0 = *reinterpret_cast<const float2*>(Yi + ib);
    float2 b1 = *reinterpret_cast<const float2*>(Yi + ib + W);
    Yo[idx] = 0.25f * (b0.x + b0.y + b1.x + b1.y);
}

// Final: per (b,c) compute prod over levels of relu(mean)^w, mean over 48, 1 - result.
__launch_bounds__(64)
__global__ void finalize_kernel(const float* __restrict__ acc, float* __restrict__ out)
{
    const int lane = threadIdx.x;
    float prod = 0.f;
    if (lane < 48) {
        const float npix[5] = {252004.f, 60516.f, 13924.f, 2916.f, 484.f};
        const float wgt[5]  = {0.0448f, 0.2856f, 0.3001f, 0.2363f, 0.1333f};
        prod = 1.f;
#pragma unroll
        for (int l = 0; l < 5; ++l) {
            // levels 0..3 use cs mean, level 4 uses ssim mean
            float v = (l < 4) ? acc[l * 96 + lane * 2 + 1] : acc[l * 96 + lane * 2 + 0];
            v = v / npix[l];
            v = fmaxf(v, 0.f);
            prod *= powf(v, wgt[l]);
        }
    }
#pragma unroll
    for (int off = 32; off; off >>= 1) prod += __shfl_down(prod, off);
    if (lane == 0) out[0] = 1.f - prod / 48.f;
}

extern "C" void kernel_launch(void* const* d_in, const int* in_sizes, int n_in,
                              void* d_out, int out_size, void* d_ws, size_t ws_size,
                              hipStream_t stream)
{
    const float* gen = (const float*)d_in[0];
    const float* gt  = (const float*)d_in[1];
    float* out = (float*)d_out;

    char* ws = (char*)d_ws;
    float* acc = (float*)ws;                 // 5*48*2 floats = 1920 B
    float* p   = (float*)(ws + 2048);
    float* g1 = p; p += (size_t)48 * 256 * 256;
    float* t1 = p; p += (size_t)48 * 256 * 256;
    float* g2 = p; p += (size_t)48 * 128 * 128;
    float* t2 = p; p += (size_t)48 * 128 * 128;
    float* g3 = p; p += (size_t)48 * 64 * 64;
    float* t3 = p; p += (size_t)48 * 64 * 64;
    float* g4 = p; p += (size_t)48 * 32 * 32;
    float* t4 = p; p += (size_t)48 * 32 * 32;

    hipMemsetAsync(acc, 0, 5 * 48 * 2 * sizeof(float), stream);

    auto launch_ssim = [&](const float* X, const float* Y, int H, int lvl) {
        int Hs = H - 10;
        dim3 grid((Hs + TW - 1) / TW, (Hs + TH - 1) / TH, 48);
        ssim_level_kernel<<<grid, 256, 0, stream>>>(X, Y, H, H, Hs, Hs, acc + lvl * 96);
    };
    auto launch_down = [&](const float* Xi, const float* Yi, float* Xo, float* Yo, int Ho) {
        int n = 48 * Ho * Ho;
        down_kernel<<<(n + 255) / 256, 256, 0, stream>>>(Xi, Yi, Xo, Yo, Ho, Ho, n);
    };

    launch_ssim(gen, gt, 512, 0);
    launch_down(gen, gt, g1, t1, 256);
    launch_ssim(g1, t1, 256, 1);
    launch_down(g1, t1, g2, t2, 128);
    launch_ssim(g2, t2, 128, 2);
    launch_down(g2, t2, g3, t3, 64);
    launch_ssim(g3, t3, 64, 3);
    launch_down(g3, t3, g4, t4, 32);
    launch_ssim(g4, t4, 32, 4);
    finalize_kernel<<<1, 64, 0, stream>>>(acc, out);
}

// Round 4
// 350.104 us; speedup vs baseline: 1.3708x; 1.3708x over previous
//
#include <hip/hip_runtime.h>

// MS-SSIM, B=16 C=3 H=W=512, f32, win=11 sigma=1.5, 5 levels.
// Structure: per level, one fused kernel:
//   phase 1: stage input x/y tile into LDS
//   phase 2: per-thread column walk: horizontal 11-tap blur of {x,y,xx,yy,xy}
//            into an 11-deep REGISTER ring (all indices parse-time constants
//            -> SROA promotes; rule #20), vertical 11-tap blur from the ring,
//            ssim/cs, accumulate.
// acc layout in ws: [level][48][2] floats (ssim_sum, cs_sum), then pyramid.

#define TW 32               // output tile width (one column per thread)
#define TH 64               // output tile height
#define RPT 8               // output rows per thread
#define HALO 10
#define IW (TW + HALO)      // 42 input cols
#define IH (TH + HALO)      // 74 input rows
#define ISTR (IW + 1)       // 43: pad

// Gaussian window, size 11, sigma 1.5, normalized (computed in double, rounded).
__device__ __constant__ float G11[11] = {
    0.001028380f, 0.007598758f, 0.036000773f, 0.109360680f, 0.213005529f,
    0.266011731f,
    0.213005529f, 0.109360680f, 0.036000773f, 0.007598758f, 0.001028380f
};

__device__ __forceinline__ float fastdiv(float a, float b) {
    float r = __builtin_amdgcn_rcpf(b);
    r = r * __builtin_fmaf(-b, r, 2.0f);   // one Newton step -> ~f32-exact
    return a * r;
}

// horizontal 11-tap blur of {x,y,xx,yy,xy} at row (ROW), col tx -> ring slot SLOT
// SLOT must be a literal/ICE so rb*[SLOT] is a constant GEP at IR-gen.
#define HBLUR(ROW, SLOT) do {                                              \
    const float* px_ = &sx[(ROW) * ISTR + tx];                             \
    const float* py_ = &sy[(ROW) * ISTR + tx];                             \
    float bx_ = 0.f, by_ = 0.f, bxx_ = 0.f, byy_ = 0.f, bxy_ = 0.f;        \
    _Pragma("unroll")                                                      \
    for (int t_ = 0; t_ < 11; ++t_) {                                      \
        float w_  = G11[t_];                                               \
        float xv_ = px_[t_];                                               \
        float yv_ = py_[t_];                                               \
        float wx_ = w_ * xv_;                                              \
        float wy_ = w_ * yv_;                                              \
        bx_  += wx_;                                                       \
        by_  += wy_;                                                       \
        bxx_ = __builtin_fmaf(wx_, xv_, bxx_);                             \
        byy_ = __builtin_fmaf(wy_, yv_, byy_);                             \
        bxy_ = __builtin_fmaf(wx_, yv_, bxy_);                             \
    }                                                                      \
    rbx[(SLOT)] = bx_; rby[(SLOT)] = by_; rbxx[(SLOT)] = bxx_;             \
    rbyy[(SLOT)] = byy_; rbxy[(SLOT)] = bxy_;                              \
} while (0)

// one vertical tap: I,T literals -> (I+T)%11 is an ICE -> constant GEP
#define VTAP(I, T) do {                                                    \
    const float w_ = G11[(T)];                                             \
    m1  = __builtin_fmaf(w_, rbx [((I)+(T)) % 11], m1);                    \
    m2  = __builtin_fmaf(w_, rby [((I)+(T)) % 11], m2);                    \
    qxx = __builtin_fmaf(w_, rbxx[((I)+(T)) % 11], qxx);                   \
    qyy = __builtin_fmaf(w_, rbyy[((I)+(T)) % 11], qyy);                   \
    qxy = __builtin_fmaf(w_, rbxy[((I)+(T)) % 11], qxy);                   \
} while (0)

#define STEP(I) do {                                                       \
    HBLUR(g0 + 10 + (I), (10 + (I)) % 11);                                 \
    float m1 = 0.f, m2 = 0.f, qxx = 0.f, qyy = 0.f, qxy = 0.f;             \
    VTAP(I,0); VTAP(I,1); VTAP(I,2); VTAP(I,3); VTAP(I,4); VTAP(I,5);      \
    VTAP(I,6); VTAP(I,7); VTAP(I,8); VTAP(I,9); VTAP(I,10);                \
    if (colok && (oy + g0 + (I)) < Hs) {                                   \
        const float C1 = 0.0001f, C2 = 0.0009f;                            \
        float mu1s = m1 * m1, mu2s = m2 * m2, mu12 = m1 * m2;              \
        float s1  = qxx - mu1s;                                            \
        float s2  = qyy - mu2s;                                            \
        float s12 = qxy - mu12;                                            \
        float cs  = fastdiv(2.f * s12 + C2, s1 + s2 + C2);                 \
        float ss  = fastdiv((2.f * mu12 + C1) * cs, mu1s + mu2s + C1);     \
        ssum += ss;                                                        \
        csum += cs;                                                        \
    }                                                                      \
} while (0)

__global__ __launch_bounds__(256)
void ssim_level_kernel(const float* __restrict__ X, const float* __restrict__ Y,
                       int H, int W, int Hs, int Ws, float* __restrict__ acc)
{
    __shared__ float sx[IH * ISTR];
    __shared__ float sy[IH * ISTR];
    __shared__ float red[2][4];

    const int bc  = blockIdx.z;
    const int ox  = blockIdx.x * TW;
    const int oy  = blockIdx.y * TH;
    const int tid = threadIdx.x;
    const size_t base = (size_t)bc * H * W;

    // ---- stage 74x42 input tile of X and Y (clamped; clamped texels only
    // feed masked-out outputs) ----
    for (int idx = tid; idx < IH * IW; idx += 256) {
        int r = idx / IW;
        int c = idx - r * IW;
        int gr = oy + r; if (gr > H - 1) gr = H - 1;
        int gc = ox + c; if (gc > W - 1) gc = W - 1;
        size_t g = base + (size_t)gr * W + gc;
        sx[r * ISTR + c] = X[g];
        sy[r * ISTR + c] = Y[g];
    }
    __syncthreads();

    const int tx = tid & 31;        // column within tile
    const int ty = tid >> 5;        // row-group 0..7
    const int g0 = ty * RPT;        // first output row of this thread

    // ---- 11-deep register ring of 5 horizontally-blurred quantities ----
    float rbx[11], rby[11], rbxx[11], rbyy[11], rbxy[11];

    HBLUR(g0 + 0, 0); HBLUR(g0 + 1, 1); HBLUR(g0 + 2, 2); HBLUR(g0 + 3, 3);
    HBLUR(g0 + 4, 4); HBLUR(g0 + 5, 5); HBLUR(g0 + 6, 6); HBLUR(g0 + 7, 7);
    HBLUR(g0 + 8, 8); HBLUR(g0 + 9, 9);

    const bool colok = (ox + tx) < Ws;
    float ssum = 0.f, csum = 0.f;

    STEP(0); STEP(1); STEP(2); STEP(3);
    STEP(4); STEP(5); STEP(6); STEP(7);

    // ---- block reduction: wave64 shfl, then cross-wave via LDS ----
#pragma unroll
    for (int off = 32; off; off >>= 1) {
        ssum += __shfl_down(ssum, off);
        csum += __shfl_down(csum, off);
    }
    if ((tid & 63) == 0) {
        red[0][tid >> 6] = ssum;
        red[1][tid >> 6] = csum;
    }
    __syncthreads();
    if (tid == 0) {
        float s = red[0][0] + red[0][1] + red[0][2] + red[0][3];
        float c = red[1][0] + red[1][1] + red[1][2] + red[1][3];
        atomicAdd(&acc[bc * 2 + 0], s);
        atomicAdd(&acc[bc * 2 + 1], c);
    }
}

// 2x2 avg-pool, stride 2, no padding (all level sizes even). Both tensors in one pass.
__launch_bounds__(256)
__global__ void down_kernel(const float* __restrict__ Xi, const float* __restrict__ Yi,
                            float* __restrict__ Xo, float* __restrict__ Yo,
                            int Ho, int Wo, int n)
{
    int idx = blockIdx.x * 256 + threadIdx.x;
    if (idx >= n) return;
    int w  = idx % Wo;
    int t  = idx / Wo;
    int h  = t % Ho;
    int bc = t / Ho;
    int W  = Wo * 2;
    size_t ib = (size_t)bc * (4 * Ho * Wo) + (size_t)(2 * h) * W + 2 * w;
    float2 a0 = *reinterpret_cast<const float2*>(Xi + ib);
    float2 a1 = *reinterpret_cast<const float2*>(Xi + ib + W);
    Xo[idx] = 0.25f * (a0.x + a0.y + a1.x + a1.y);
    float2 b0 = *reinterpret_cast<const float2*>(Yi + ib);
    float2 b1 = *reinterpret_cast<const float2*>(Yi + ib + W);
    Yo[idx] = 0.25f * (b0.x + b0.y + b1.x + b1.y);
}

// Final: per (b,c) compute prod over levels of relu(mean)^w, mean over 48, 1 - result.
__launch_bounds__(64)
__global__ void finalize_kernel(const float* __restrict__ acc, float* __restrict__ out)
{
    const int lane = threadIdx.x;
    float prod = 0.f;
    if (lane < 48) {
        const float npix[5] = {252004.f, 60516.f, 13924.f, 2916.f, 484.f};
        const float wgt[5]  = {0.0448f, 0.2856f, 0.3001f, 0.2363f, 0.1333f};
        prod = 1.f;
#pragma unroll
        for (int l = 0; l < 5; ++l) {
            // levels 0..3 use cs mean, level 4 uses ssim mean
            float v = (l < 4) ? acc[l * 96 + lane * 2 + 1] : acc[l * 96 + lane * 2 + 0];
            v = v / npix[l];
            v = fmaxf(v, 0.f);
            prod *= powf(v, wgt[l]);
        }
    }
#pragma unroll
    for (int off = 32; off; off >>= 1) prod += __shfl_down(prod, off);
    if (lane == 0) out[0] = 1.f - prod / 48.f;
}

extern "C" void kernel_launch(void* const* d_in, const int* in_sizes, int n_in,
                              void* d_out, int out_size, void* d_ws, size_t ws_size,
                              hipStream_t stream)
{
    const float* gen = (const float*)d_in[0];
    const float* gt  = (const float*)d_in[1];
    float* out = (float*)d_out;

    char* ws = (char*)d_ws;
    float* acc = (float*)ws;                 // 5*48*2 floats = 1920 B
    float* p   = (float*)(ws + 2048);
    float* g1 = p; p += (size_t)48 * 256 * 256;
    float* t1 = p; p += (size_t)48 * 256 * 256;
    float* g2 = p; p += (size_t)48 * 128 * 128;
    float* t2 = p; p += (size_t)48 * 128 * 128;
    float* g3 = p; p += (size_t)48 * 64 * 64;
    float* t3 = p; p += (size_t)48 * 64 * 64;
    float* g4 = p; p += (size_t)48 * 32 * 32;
    float* t4 = p; p += (size_t)48 * 32 * 32;

    hipMemsetAsync(acc, 0, 5 * 48 * 2 * sizeof(float), stream);

    auto launch_ssim = [&](const float* X, const float* Y, int H, int lvl) {
        int Hs = H - 10;
        dim3 grid((Hs + TW - 1) / TW, (Hs + TH - 1) / TH, 48);
        ssim_level_kernel<<<grid, 256, 0, stream>>>(X, Y, H, H, Hs, Hs, acc + lvl * 96);
    };
    auto launch_down = [&](const float* Xi, const float* Yi, float* Xo, float* Yo, int Ho) {
        int n = 48 * Ho * Ho;
        down_kernel<<<(n + 255) / 256, 256, 0, stream>>>(Xi, Yi, Xo, Yo, Ho, Ho, n);
    };

    launch_ssim(gen, gt, 512, 0);
    launch_down(gen, gt, g1, t1, 256);
    launch_ssim(g1, t1, 256, 1);
    launch_down(g1, t1, g2, t2, 128);
    launch_ssim(g2, t2, 128, 2);
    launch_down(g2, t2, g3, t3, 64);
    launch_ssim(g3, t3, 64, 3);
    launch_down(g3, t3, g4, t4, 32);
    launch_ssim(g4, t4, 32, 4);
    finalize_kernel<<<1, 64, 0, stream>>>(acc, out);
}

// Round 5
// 341.640 us; speedup vs baseline: 1.4048x; 1.0248x over previous
//
#include <hip/hip_runtime.h>

// MS-SSIM, B=16 C=3 H=W=512, f32, win=11 sigma=1.5, 5 levels.
// Structure: per level, one fused kernel:
//   phase 1: stage input x/y tile into LDS as INTERLEAVED float2 (1 ds_read_b64
//            serves both tensors per tap)
//   phase 2: per-thread column walk, 16 output rows per thread: horizontal
//            11-tap blur of {x,y,xx,yy,xy} into an 11-deep REGISTER ring
//            (all indices parse-time constants -> SROA promotes; rule #20),
//            vertical 11-tap blur from the ring, ssim/cs, accumulate.
// acc layout in ws: [level][48][2] floats (ssim_sum, cs_sum), then pyramid.

#define TW 32               // output tile width (one column per thread)
#define TH 128              // output tile height
#define RPT 16              // output rows per thread (8 row-groups)
#define HALO 10
#define IW (TW + HALO)      // 42 input cols
#define IH (TH + HALO)      // 138 input rows
#define ISTR (IW + 1)       // 43 float2s per row: pad

// Gaussian window, size 11, sigma 1.5, normalized (computed in double, rounded).
__device__ __constant__ float G11[11] = {
    0.001028380f, 0.007598758f, 0.036000773f, 0.109360680f, 0.213005529f,
    0.266011731f,
    0.213005529f, 0.109360680f, 0.036000773f, 0.007598758f, 0.001028380f
};

__device__ __forceinline__ float fastdiv(float a, float b) {
    float r = __builtin_amdgcn_rcpf(b);
    r = r * __builtin_fmaf(-b, r, 2.0f);   // one Newton step -> ~f32-exact
    return a * r;
}

// horizontal 11-tap blur of {x,y,xx,yy,xy} at row (ROW), col tx -> ring slot SLOT
// SLOT must be a literal/ICE so rb*[SLOT] is a constant GEP at IR-gen.
#define HBLUR(ROW, SLOT) do {                                              \
    const float2* pxy_ = &sxy[(ROW) * ISTR + tx];                          \
    float bx_ = 0.f, by_ = 0.f, bxx_ = 0.f, byy_ = 0.f, bxy_ = 0.f;        \
    _Pragma("unroll")                                                      \
    for (int t_ = 0; t_ < 11; ++t_) {                                      \
        float w_  = G11[t_];                                               \
        float2 v_ = pxy_[t_];                                              \
        float wx_ = w_ * v_.x;                                             \
        float wy_ = w_ * v_.y;                                             \
        bx_  += wx_;                                                       \
        by_  += wy_;                                                       \
        bxx_ = __builtin_fmaf(wx_, v_.x, bxx_);                            \
        byy_ = __builtin_fmaf(wy_, v_.y, byy_);                            \
        bxy_ = __builtin_fmaf(wx_, v_.y, bxy_);                            \
    }                                                                      \
    rbx[(SLOT)] = bx_; rby[(SLOT)] = by_; rbxx[(SLOT)] = bxx_;             \
    rbyy[(SLOT)] = byy_; rbxy[(SLOT)] = bxy_;                              \
} while (0)

// one vertical tap: I,T literals -> (I+T)%11 is an ICE -> constant GEP
#define VTAP(I, T) do {                                                    \
    const float w_ = G11[(T)];                                             \
    m1  = __builtin_fmaf(w_, rbx [((I)+(T)) % 11], m1);                    \
    m2  = __builtin_fmaf(w_, rby [((I)+(T)) % 11], m2);                    \
    qxx = __builtin_fmaf(w_, rbxx[((I)+(T)) % 11], qxx);                   \
    qyy = __builtin_fmaf(w_, rbyy[((I)+(T)) % 11], qyy);                   \
    qxy = __builtin_fmaf(w_, rbxy[((I)+(T)) % 11], qxy);                   \
} while (0)

#define STEP(I) do {                                                       \
    HBLUR(g0 + 10 + (I), (10 + (I)) % 11);                                 \
    float m1 = 0.f, m2 = 0.f, qxx = 0.f, qyy = 0.f, qxy = 0.f;             \
    VTAP(I,0); VTAP(I,1); VTAP(I,2); VTAP(I,3); VTAP(I,4); VTAP(I,5);      \
    VTAP(I,6); VTAP(I,7); VTAP(I,8); VTAP(I,9); VTAP(I,10);                \
    if (colok && (oy + g0 + (I)) < Hs) {                                   \
        const float C1 = 0.0001f, C2 = 0.0009f;                            \
        float mu1s = m1 * m1, mu2s = m2 * m2, mu12 = m1 * m2;              \
        float s1  = qxx - mu1s;                                            \
        float s2  = qyy - mu2s;                                            \
        float s12 = qxy - mu12;                                            \
        float cs  = fastdiv(2.f * s12 + C2, s1 + s2 + C2);                 \
        float ss  = fastdiv((2.f * mu12 + C1) * cs, mu1s + mu2s + C1);     \
        ssum += ss;                                                        \
        csum += cs;                                                        \
    }                                                                      \
} while (0)

__global__ __launch_bounds__(256)
void ssim_level_kernel(const float* __restrict__ X, const float* __restrict__ Y,
                       int H, int W, int Hs, int Ws, float* __restrict__ acc)
{
    __shared__ float2 sxy[IH * ISTR];
    __shared__ float red[2][4];

    const int bc  = blockIdx.z;
    const int ox  = blockIdx.x * TW;
    const int oy  = blockIdx.y * TH;
    const int tid = threadIdx.x;
    const size_t base = (size_t)bc * H * W;

    // ---- stage 138x42 input tile, x/y interleaved (clamped; clamped texels
    // only feed masked-out outputs) ----
    for (int idx = tid; idx < IH * IW; idx += 256) {
        int r = idx / IW;
        int c = idx - r * IW;
        int gr = oy + r; if (gr > H - 1) gr = H - 1;
        int gc = ox + c; if (gc > W - 1) gc = W - 1;
        size_t g = base + (size_t)gr * W + gc;
        sxy[r * ISTR + c] = make_float2(X[g], Y[g]);
    }
    __syncthreads();

    const int tx = tid & 31;        // column within tile
    const int ty = tid >> 5;        // row-group 0..7
    const int g0 = ty * RPT;        // first output row of this thread

    // ---- 11-deep register ring of 5 horizontally-blurred quantities ----
    float rbx[11], rby[11], rbxx[11], rbyy[11], rbxy[11];

    HBLUR(g0 + 0, 0); HBLUR(g0 + 1, 1); HBLUR(g0 + 2, 2); HBLUR(g0 + 3, 3);
    HBLUR(g0 + 4, 4); HBLUR(g0 + 5, 5); HBLUR(g0 + 6, 6); HBLUR(g0 + 7, 7);
    HBLUR(g0 + 8, 8); HBLUR(g0 + 9, 9);

    const bool colok = (ox + tx) < Ws;
    float ssum = 0.f, csum = 0.f;

    STEP(0);  STEP(1);  STEP(2);  STEP(3);
    STEP(4);  STEP(5);  STEP(6);  STEP(7);
    STEP(8);  STEP(9);  STEP(10); STEP(11);
    STEP(12); STEP(13); STEP(14); STEP(15);

    // ---- block reduction: wave64 shfl, then cross-wave via LDS ----
#pragma unroll
    for (int off = 32; off; off >>= 1) {
        ssum += __shfl_down(ssum, off);
        csum += __shfl_down(csum, off);
    }
    if ((tid & 63) == 0) {
        red[0][tid >> 6] = ssum;
        red[1][tid >> 6] = csum;
    }
    __syncthreads();
    if (tid == 0) {
        float s = red[0][0] + red[0][1] + red[0][2] + red[0][3];
        float c = red[1][0] + red[1][1] + red[1][2] + red[1][3];
        atomicAdd(&acc[bc * 2 + 0], s);
        atomicAdd(&acc[bc * 2 + 1], c);
    }
}

// 2x2 avg-pool, stride 2, no padding (all level sizes even). Both tensors in one pass.
__launch_bounds__(256)
__global__ void down_kernel(const float* __restrict__ Xi, const float* __restrict__ Yi,
                            float* __restrict__ Xo, float* __restrict__ Yo,
                            int Ho, int Wo, int n)
{
    int idx = blockIdx.x * 256 + threadIdx.x;
    if (idx >= n) return;
    int w  = idx % Wo;
    int t  = idx / Wo;
    int h  = t % Ho;
    int bc = t / Ho;
    int W  = Wo * 2;
    size_t ib = (size_t)bc * (4 * Ho * Wo) + (size_t)(2 * h) * W + 2 * w;
    float2 a0 = *reinterpret_cast<const float2*>(Xi + ib);
    float2 a1 = *reinterpret_cast<const float2*>(Xi + ib + W);
    Xo[idx] = 0.25f * (a0.x + a0.y + a1.x + a1.y);
    float2 b0 = *reinterpret_cast<const float2*>(Yi + ib);
    float2 b1 = *reinterpret_cast<const float2*>(Yi + ib + W);
    Yo[idx] = 0.25f * (b0.x + b0.y + b1.x + b1.y);
}

// Final: per (b,c) compute prod over levels of relu(mean)^w, mean over 48, 1 - result.
__launch_bounds__(64)
__global__ void finalize_kernel(const float* __restrict__ acc, float* __restrict__ out)
{
    const int lane = threadIdx.x;
    float prod = 0.f;
    if (lane < 48) {
        const float npix[5] = {252004.f, 60516.f, 13924.f, 2916.f, 484.f};
        const float wgt[5]  = {0.0448f, 0.2856f, 0.3001f, 0.2363f, 0.1333f};
        prod = 1.f;
#pragma unroll
        for (int l = 0; l < 5; ++l) {
            // levels 0..3 use cs mean, level 4 uses ssim mean
            float v = (l < 4) ? acc[l * 96 + lane * 2 + 1] : acc[l * 96 + lane * 2 + 0];
            v = v / npix[l];
            v = fmaxf(v, 0.f);
            prod *= powf(v, wgt[l]);
        }
    }
#pragma unroll
    for (int off = 32; off; off >>= 1) prod += __shfl_down(prod, off);
    if (lane == 0) out[0] = 1.f - prod / 48.f;
}

extern "C" void kernel_launch(void* const* d_in, const int* in_sizes, int n_in,
                              void* d_out, int out_size, void* d_ws, size_t ws_size,
                              hipStream_t stream)
{
    const float* gen = (const float*)d_in[0];
    const float* gt  = (const float*)d_in[1];
    float* out = (float*)d_out;

    char* ws = (char*)d_ws;
    float* acc = (float*)ws;                 // 5*48*2 floats = 1920 B
    float* p   = (float*)(ws + 2048);
    float* g1 = p; p += (size_t)48 * 256 * 256;
    float* t1 = p; p += (size_t)48 * 256 * 256;
    float* g2 = p; p += (size_t)48 * 128 * 128;
    float* t2 = p; p += (size_t)48 * 128 * 128;
    float* g3 = p; p += (size_t)48 * 64 * 64;
    float* t3 = p; p += (size_t)48 * 64 * 64;
    float* g4 = p; p += (size_t)48 * 32 * 32;
    float* t4 = p; p += (size_t)48 * 32 * 32;

    hipMemsetAsync(acc, 0, 5 * 48 * 2 * sizeof(float), stream);

    auto launch_ssim = [&](const float* X, const float* Y, int H, int lvl) {
        int Hs = H - 10;
        dim3 grid((Hs + TW - 1) / TW, (Hs + TH - 1) / TH, 48);
        ssim_level_kernel<<<grid, 256, 0, stream>>>(X, Y, H, H, Hs, Hs, acc + lvl * 96);
    };
    auto launch_down = [&](const float* Xi, const float* Yi, float* Xo, float* Yo, int Ho) {
        int n = 48 * Ho * Ho;
        down_kernel<<<(n + 255) / 256, 256, 0, stream>>>(Xi, Yi, Xo, Yo, Ho, Ho, n);
    };

    launch_ssim(gen, gt, 512, 0);
    launch_down(gen, gt, g1, t1, 256);
    launch_ssim(g1, t1, 256, 1);
    launch_down(g1, t1, g2, t2, 128);
    launch_ssim(g2, t2, 128, 2);
    launch_down(g2, t2, g3, t3, 64);
    launch_ssim(g3, t3, 64, 3);
    launch_down(g3, t3, g4, t4, 32);
    launch_ssim(g4, t4, 32, 4);
    finalize_kernel<<<1, 64, 0, stream>>>(acc, out);
}

// Round 6
// 283.742 us; speedup vs baseline: 1.6915x; 1.2040x over previous
//
#include <hip/hip_runtime.h>

// MS-SSIM, B=16 C=3 H=W=512, f32, win=11 sigma=1.5, 5 levels.
// Per level ONE fused kernel:
//   phase 1: stage input x/y tile into LDS as INTERLEAVED float2 (ds_read_b64
//            serves both tensors per tap), float2-pair vectorized staging
//   phase 2: per-thread column walk, 8 output rows/thread: horizontal 11-tap
//            blur of {x,y,xx,yy,xy} into an 11-deep REGISTER ring (indices are
//            parse-time constants -> SROA promotes; rule #20), vertical 11-tap
//            blur from ring, ssim/cs, accumulate
//   phase 3: fused 2x2 avg-pool epilogue writes next level's inputs from LDS
// acc layout in ws: [level][48][2] floats (ssim_sum, cs_sum), then pyramid.

#define TW 32               // output tile width (one column per thread)
#define TH 64               // output tile height
#define RPT 8               // output rows per thread (8 row-groups)
#define HALO 10
#define IW (TW + HALO)      // 42 input cols
#define IH (TH + HALO)      // 74 input rows
#define ISTR (IW + 1)       // 43 float2s per row (pad)

// Gaussian window, size 11, sigma 1.5, normalized (computed in double, rounded).
__device__ __constant__ float G11[11] = {
    0.001028380f, 0.007598758f, 0.036000773f, 0.109360680f, 0.213005529f,
    0.266011731f,
    0.213005529f, 0.109360680f, 0.036000773f, 0.007598758f, 0.001028380f
};

__device__ __forceinline__ float fastdiv(float a, float b) {
    float r = __builtin_amdgcn_rcpf(b);
    r = r * __builtin_fmaf(-b, r, 2.0f);   // one Newton step -> ~f32-exact
    return a * r;
}

// horizontal 11-tap blur of {x,y,xx,yy,xy} at row (ROW), col tx -> ring slot SLOT
// SLOT must be a literal/ICE so rb*[SLOT] is a constant GEP at IR-gen.
#define HBLUR(ROW, SLOT) do {                                              \
    const float2* pxy_ = &sxy[(ROW) * ISTR + tx];                          \
    float bx_ = 0.f, by_ = 0.f, bxx_ = 0.f, byy_ = 0.f, bxy_ = 0.f;        \
    _Pragma("unroll")                                                      \
    for (int t_ = 0; t_ < 11; ++t_) {                                      \
        float w_  = G11[t_];                                               \
        float2 v_ = pxy_[t_];                                              \
        float wx_ = w_ * v_.x;                                             \
        float wy_ = w_ * v_.y;                                             \
        bx_  += wx_;                                                       \
        by_  += wy_;                                                       \
        bxx_ = __builtin_fmaf(wx_, v_.x, bxx_);                            \
        byy_ = __builtin_fmaf(wy_, v_.y, byy_);                            \
        bxy_ = __builtin_fmaf(wx_, v_.y, bxy_);                            \
    }                                                                      \
    rbx[(SLOT)] = bx_; rby[(SLOT)] = by_; rbxx[(SLOT)] = bxx_;             \
    rbyy[(SLOT)] = byy_; rbxy[(SLOT)] = bxy_;                              \
} while (0)

// one vertical tap: I,T literals -> (I+T)%11 is an ICE -> constant GEP
#define VTAP(I, T) do {                                                    \
    const float w_ = G11[(T)];                                             \
    m1  = __builtin_fmaf(w_, rbx [((I)+(T)) % 11], m1);                    \
    m2  = __builtin_fmaf(w_, rby [((I)+(T)) % 11], m2);                    \
    qxx = __builtin_fmaf(w_, rbxx[((I)+(T)) % 11], qxx);                   \
    qyy = __builtin_fmaf(w_, rbyy[((I)+(T)) % 11], qyy);                   \
    qxy = __builtin_fmaf(w_, rbxy[((I)+(T)) % 11], qxy);                   \
} while (0)

#define STEP(I) do {                                                       \
    HBLUR(g0 + 10 + (I), (10 + (I)) % 11);                                 \
    float m1 = 0.f, m2 = 0.f, qxx = 0.f, qyy = 0.f, qxy = 0.f;             \
    VTAP(I,0); VTAP(I,1); VTAP(I,2); VTAP(I,3); VTAP(I,4); VTAP(I,5);      \
    VTAP(I,6); VTAP(I,7); VTAP(I,8); VTAP(I,9); VTAP(I,10);                \
    if (colok && (oy + g0 + (I)) < Hs) {                                   \
        const float C1 = 0.0001f, C2 = 0.0009f;                            \
        float mu1s = m1 * m1, mu2s = m2 * m2, mu12 = m1 * m2;              \
        float s1  = qxx - mu1s;                                            \
        float s2  = qyy - mu2s;                                            \
        float s12 = qxy - mu12;                                            \
        float cs  = fastdiv(2.f * s12 + C2, s1 + s2 + C2);                 \
        float ss  = fastdiv((2.f * mu12 + C1) * cs, mu1s + mu2s + C1);     \
        ssum += ss;                                                        \
        csum += cs;                                                        \
    }                                                                      \
} while (0)

__global__ __launch_bounds__(256)
void ssim_level_kernel(const float* __restrict__ X, const float* __restrict__ Y,
                       int H, int W, int Hs, int Ws, float* __restrict__ acc,
                       float* __restrict__ Xo, float* __restrict__ Yo,
                       int Wp, int do_pool)
{
    __shared__ float2 sxy[IH * ISTR];
    __shared__ float red[2][4];

    const int bc  = blockIdx.z;
    const int ox  = blockIdx.x * TW;
    const int oy  = blockIdx.y * TH;
    const int tid = threadIdx.x;
    const size_t base = (size_t)bc * H * W;

    // ---- stage 74x42 tile, x/y interleaved, float2-pair vectorized.
    // Row clamp + even-col clamp keep loads in-bounds; clamped texels only
    // ever feed masked-out outputs (verified: valid outputs touch only real
    // texels; pool epilogue touches only unclamped region). ----
    for (int p = tid; p < IH * 21; p += 256) {
        int r  = p / 21;
        int c2 = p - r * 21;
        int gr = oy + r;      if (gr > H - 1) gr = H - 1;
        int gc = ox + 2 * c2; if (gc > W - 2) gc = W - 2;   // stays even
        size_t g = base + (size_t)gr * W + gc;
        float2 xv = *reinterpret_cast<const float2*>(X + g);
        float2 yv = *reinterpret_cast<const float2*>(Y + g);
        float2* dst = &sxy[r * ISTR + 2 * c2];
        dst[0] = make_float2(xv.x, yv.x);
        dst[1] = make_float2(xv.y, yv.y);
    }
    __syncthreads();

    const int tx = tid & 31;        // column within tile
    const int ty = tid >> 5;        // row-group 0..7
    const int g0 = ty * RPT;        // first output row of this thread

    // ---- 11-deep register ring of 5 horizontally-blurred quantities ----
    float rbx[11], rby[11], rbxx[11], rbyy[11], rbxy[11];

    HBLUR(g0 + 0, 0); HBLUR(g0 + 1, 1); HBLUR(g0 + 2, 2); HBLUR(g0 + 3, 3);
    HBLUR(g0 + 4, 4); HBLUR(g0 + 5, 5); HBLUR(g0 + 6, 6); HBLUR(g0 + 7, 7);
    HBLUR(g0 + 8, 8); HBLUR(g0 + 9, 9);

    const bool colok = (ox + tx) < Ws;
    float ssum = 0.f, csum = 0.f;

    STEP(0); STEP(1); STEP(2); STEP(3);
    STEP(4); STEP(5); STEP(6); STEP(7);

    // ---- fused 2x2 avg-pool epilogue: this block's tile covers pool rows
    // oy/2..oy/2+31, cols ox/2..ox/2+15 exactly once across the grid ----
    if (do_pool) {
        int i  = tid >> 3;            // pool row 0..31
        int j0 = (tid & 7) * 2;       // pool col pair 0,2,..,14
        const float2* r0 = &sxy[(2 * i)     * ISTR + 2 * j0];
        const float2* r1 = &sxy[(2 * i + 1) * ISTR + 2 * j0];
        float2 a0 = r0[0], a1 = r0[1], b0 = r1[0], b1 = r1[1];
        float2 c0 = r0[2], c1 = r0[3], d0 = r1[2], d1 = r1[3];
        float2 xo, yo;
        xo.x = 0.25f * (a0.x + a1.x + b0.x + b1.x);
        yo.x = 0.25f * (a0.y + a1.y + b0.y + b1.y);
        xo.y = 0.25f * (c0.x + c1.x + d0.x + d1.x);
        yo.y = 0.25f * (c0.y + c1.y + d0.y + d1.y);
        size_t po = (size_t)bc * Wp * Wp + (size_t)((oy >> 1) + i) * Wp + (ox >> 1) + j0;
        *reinterpret_cast<float2*>(Xo + po) = xo;
        *reinterpret_cast<float2*>(Yo + po) = yo;
    }

    // ---- block reduction: wave64 shfl, then cross-wave via LDS ----
#pragma unroll
    for (int off = 32; off; off >>= 1) {
        ssum += __shfl_down(ssum, off);
        csum += __shfl_down(csum, off);
    }
    if ((tid & 63) == 0) {
        red[0][tid >> 6] = ssum;
        red[1][tid >> 6] = csum;
    }
    __syncthreads();
    if (tid == 0) {
        float s = red[0][0] + red[0][1] + red[0][2] + red[0][3];
        float c = red[1][0] + red[1][1] + red[1][2] + red[1][3];
        atomicAdd(&acc[bc * 2 + 0], s);
        atomicAdd(&acc[bc * 2 + 1], c);
    }
}

// Final: per (b,c) compute prod over levels of relu(mean)^w, mean over 48, 1 - result.
__launch_bounds__(64)
__global__ void finalize_kernel(const float* __restrict__ acc, float* __restrict__ out)
{
    const int lane = threadIdx.x;
    float prod = 0.f;
    if (lane < 48) {
        const float npix[5] = {252004.f, 60516.f, 13924.f, 2916.f, 484.f};
        const float wgt[5]  = {0.0448f, 0.2856f, 0.3001f, 0.2363f, 0.1333f};
        prod = 1.f;
#pragma unroll
        for (int l = 0; l < 5; ++l) {
            // levels 0..3 use cs mean, level 4 uses ssim mean
            float v = (l < 4) ? acc[l * 96 + lane * 2 + 1] : acc[l * 96 + lane * 2 + 0];
            v = v / npix[l];
            v = fmaxf(v, 0.f);
            prod *= powf(v, wgt[l]);
        }
    }
#pragma unroll
    for (int off = 32; off; off >>= 1) prod += __shfl_down(prod, off);
    if (lane == 0) out[0] = 1.f - prod / 48.f;
}

extern "C" void kernel_launch(void* const* d_in, const int* in_sizes, int n_in,
                              void* d_out, int out_size, void* d_ws, size_t ws_size,
                              hipStream_t stream)
{
    const float* gen = (const float*)d_in[0];
    const float* gt  = (const float*)d_in[1];
    float* out = (float*)d_out;

    char* ws = (char*)d_ws;
    float* acc = (float*)ws;                 // 5*48*2 floats = 1920 B
    float* p   = (float*)(ws + 2048);
    float* g1 = p; p += (size_t)48 * 256 * 256;
    float* t1 = p; p += (size_t)48 * 256 * 256;
    float* g2 = p; p += (size_t)48 * 128 * 128;
    float* t2 = p; p += (size_t)48 * 128 * 128;
    float* g3 = p; p += (size_t)48 * 64 * 64;
    float* t3 = p; p += (size_t)48 * 64 * 64;
    float* g4 = p; p += (size_t)48 * 32 * 32;
    float* t4 = p; p += (size_t)48 * 32 * 32;

    hipMemsetAsync(acc, 0, 5 * 48 * 2 * sizeof(float), stream);

    auto launch_ssim = [&](const float* X, const float* Y, int H, int lvl,
                           float* Xo, float* Yo) {
        int Hs = H - 10;
        dim3 grid((Hs + TW - 1) / TW, (Hs + TH - 1) / TH, 48);
        ssim_level_kernel<<<grid, 256, 0, stream>>>(X, Y, H, H, Hs, Hs,
                                                    acc + lvl * 96,
                                                    Xo, Yo, H / 2, Xo != nullptr);
    };

    launch_ssim(gen, gt, 512, 0, g1, t1);
    launch_ssim(g1, t1, 256, 1, g2, t2);
    launch_ssim(g2, t2, 128, 2, g3, t3);
    launch_ssim(g3, t3, 64, 3, g4, t4);
    launch_ssim(g4, t4, 32, 4, nullptr, nullptr);
    finalize_kernel<<<1, 64, 0, stream>>>(acc, out);
}

// Round 8
// 278.922 us; speedup vs baseline: 1.7207x; 1.0173x over previous
//
#include <hip/hip_runtime.h>

// MS-SSIM, B=16 C=3 H=W=512, f32, win=11 sigma=1.5, 5 levels.
// Levels 0-2: one fused kernel per level (stage f2-interleaved tile -> per-
//   thread column walk with 11-deep 4-quantity register ring -> ssim/cs ->
//   fused 2x2 avg-pool epilogue writes next level).
// Levels 3+4: ONE 48-block kernel: stage 64x64, L3 ssim, pool in LDS, L4 ssim,
//   direct per-(b,c) acc stores (no atomics).
// acc layout in ws: [level][48][2] floats (ssim_sum, cs_sum), then pyramid.

// Gaussian window, size 11, sigma 1.5, normalized (computed in double, rounded).
__device__ __constant__ float G11[11] = {
    0.001028380f, 0.007598758f, 0.036000773f, 0.109360680f, 0.213005529f,
    0.266011731f,
    0.213005529f, 0.109360680f, 0.036000773f, 0.007598758f, 0.001028380f
};

__device__ __forceinline__ float fastdiv(float a, float b) {
    float r = __builtin_amdgcn_rcpf(b);
    r = r * __builtin_fmaf(-b, r, 2.0f);   // one Newton step -> ~f32-exact
    return a * r;
}

// Column-strip ssim walk. tile: f2-interleaved (x,y) LDS tile; txr: (clamped)
// read column; g0: first output row of this thread; rowmax: clamp for tile row
// reads; nvalid: #valid steps (output row g0+I valid iff I<nvalid); colok:
// column mask. Ring indices are all ICEs (rule #20: SROA must promote).
template<int NS, int STR>
__device__ __forceinline__ void ssim_strip(const float2* __restrict__ tile,
                                           int txr, int g0, int rowmax,
                                           int nvalid, bool colok,
                                           float& ssum, float& csum)
{
    float rbx[11], rby[11], rbss[11], rbxy[11];

#define HB(K, SLOT) do {                                                    \
    int r_ = g0 + (K); if (r_ > rowmax) r_ = rowmax;                        \
    const float2* p_ = tile + r_ * STR + txr;                               \
    float bx_=0.f, by_=0.f, bxx_=0.f, byy_=0.f, bxy_=0.f;                   \
    _Pragma("unroll")                                                       \
    for (int t_ = 0; t_ < 11; ++t_) {                                       \
        float w_ = G11[t_];                                                 \
        float2 v_ = p_[t_];                                                 \
        float wx_ = w_ * v_.x;                                              \
        float wy_ = w_ * v_.y;                                              \
        bx_ += wx_; by_ += wy_;                                             \
        bxx_ = __builtin_fmaf(wx_, v_.x, bxx_);                             \
        byy_ = __builtin_fmaf(wy_, v_.y, byy_);                             \
        bxy_ = __builtin_fmaf(wx_, v_.y, bxy_);                             \
    }                                                                       \
    rbx[(SLOT)] = bx_; rby[(SLOT)] = by_;                                   \
    rbss[(SLOT)] = bxx_ + byy_; rbxy[(SLOT)] = bxy_;                        \
} while (0)

#define VT(I, T) do {                                                       \
    const float w_ = G11[(T)];                                              \
    m1  = __builtin_fmaf(w_, rbx [((I)+(T)) % 11], m1);                     \
    m2  = __builtin_fmaf(w_, rby [((I)+(T)) % 11], m2);                     \
    qs  = __builtin_fmaf(w_, rbss[((I)+(T)) % 11], qs);                     \
    qxy = __builtin_fmaf(w_, rbxy[((I)+(T)) % 11], qxy);                    \
} while (0)

#define ST(I)                                                               \
    if constexpr (NS > (I)) {                                               \
        HB(10 + (I), (10 + (I)) % 11);                                      \
        float m1=0.f, m2=0.f, qs=0.f, qxy=0.f;                              \
        VT(I,0); VT(I,1); VT(I,2); VT(I,3); VT(I,4); VT(I,5);               \
        VT(I,6); VT(I,7); VT(I,8); VT(I,9); VT(I,10);                       \
        if (colok && (I) < nvalid) {                                        \
            const float C1 = 0.0001f, C2 = 0.0009f;                         \
            float mu1s = m1*m1, mu2s = m2*m2, mu12 = m1*m2;                 \
            float s12  = qxy - mu12;                                        \
            float s1s2 = qs - mu1s - mu2s;                                  \
            float cs = fastdiv(2.f*s12 + C2, s1s2 + C2);                    \
            float ss = fastdiv((2.f*mu12 + C1) * cs, mu1s + mu2s + C1);     \
            ssum += ss; csum += cs;                                         \
        }                                                                   \
    }

    HB(0,0); HB(1,1); HB(2,2); HB(3,3); HB(4,4);
    HB(5,5); HB(6,6); HB(7,7); HB(8,8); HB(9,9);

    ST(0) ST(1) ST(2) ST(3) ST(4) ST(5) ST(6) ST(7)
    ST(8) ST(9) ST(10) ST(11) ST(12) ST(13) ST(14) ST(15)

#undef HB
#undef VT
#undef ST
}

#define TW 32               // output tile width (one column per thread)
#define TH 64               // output tile height
#define IW 42               // input cols (TW+10)
#define IH 74               // input rows (TH+10)
#define ISTR 43             // f2 row stride (pad)

__global__ __launch_bounds__(256)
void ssim_level_kernel(const float* __restrict__ X, const float* __restrict__ Y,
                       int H, int W, int Hs, int Ws, float* __restrict__ acc,
                       float* __restrict__ Xo, float* __restrict__ Yo,
                       int Wp, int do_pool)
{
    __shared__ float2 sxy[IH * ISTR];
    __shared__ float red[2][4];

    const int bc  = blockIdx.z;
    const int ox  = blockIdx.x * TW;
    const int oy  = blockIdx.y * TH;
    const int tid = threadIdx.x;
    const size_t base = (size_t)bc * H * W;

    // ---- stage 74x42 tile, x/y interleaved, float2-pair vectorized.
    // Row clamp + even-col clamp keep loads in-bounds; clamped texels only
    // ever feed masked-out outputs; pool region is always unclamped. ----
    for (int p = tid; p < IH * 21; p += 256) {
        int r  = p / 21;
        int c2 = p - r * 21;
        int gr = oy + r;      if (gr > H - 1) gr = H - 1;
        int gc = ox + 2 * c2; if (gc > W - 2) gc = W - 2;   // stays even
        size_t g = base + (size_t)gr * W + gc;
        float2 xv = *reinterpret_cast<const float2*>(X + g);
        float2 yv = *reinterpret_cast<const float2*>(Y + g);
        float2* dst = &sxy[r * ISTR + 2 * c2];
        dst[0] = make_float2(xv.x, yv.x);
        dst[1] = make_float2(xv.y, yv.y);
    }
    __syncthreads();

    const int tx = tid & 31;
    const int ty = tid >> 5;
    const int g0 = ty * 8;

    float ssum = 0.f, csum = 0.f;
    ssim_strip<8, ISTR>(sxy, tx, g0, IH - 1, Hs - oy - g0, (ox + tx) < Ws,
                        ssum, csum);

    // ---- fused 2x2 avg-pool epilogue: tile covers pool rows oy/2..+31,
    // cols ox/2..+15 exactly once across the grid ----
    if (do_pool) {
        int i  = tid >> 3;            // pool row 0..31
        int j0 = (tid & 7) * 2;       // pool col pair 0,2,..,14
        const float2* r0 = &sxy[(2 * i)     * ISTR + 2 * j0];
        const float2* r1 = &sxy[(2 * i + 1) * ISTR + 2 * j0];
        float2 a0 = r0[0], a1 = r0[1], b0 = r1[0], b1 = r1[1];
        float2 c0 = r0[2], c1 = r0[3], d0 = r1[2], d1 = r1[3];
        float2 xo, yo;
        xo.x = 0.25f * (a0.x + a1.x + b0.x + b1.x);
        yo.x = 0.25f * (a0.y + a1.y + b0.y + b1.y);
        xo.y = 0.25f * (c0.x + c1.x + d0.x + d1.x);
        yo.y = 0.25f * (c0.y + c1.y + d0.y + d1.y);
        size_t po = (size_t)bc * Wp * Wp + (size_t)((oy >> 1) + i) * Wp + (ox >> 1) + j0;
        *reinterpret_cast<float2*>(Xo + po) = xo;
        *reinterpret_cast<float2*>(Yo + po) = yo;
    }

    // ---- block reduction: wave64 shfl, then cross-wave via LDS ----
#pragma unroll
    for (int off = 32; off; off >>= 1) {
        ssum += __shfl_down(ssum, off);
        csum += __shfl_down(csum, off);
    }
    if ((tid & 63) == 0) {
        red[0][tid >> 6] = ssum;
        red[1][tid >> 6] = csum;
    }
    __syncthreads();
    if (tid == 0) {
        float s = red[0][0] + red[0][1] + red[0][2] + red[0][3];
        float c = red[1][0] + red[1][1] + red[1][2] + red[1][3];
        atomicAdd(&acc[bc * 2 + 0], s);
        atomicAdd(&acc[bc * 2 + 1], c);
    }
}

// ---- Levels 3+4 fused: one block per (b,c). Stage 64x64, L3 ssim (54x54),
// pool in LDS to 32x32, L4 ssim (22x22). Direct acc stores (one block/bc).
#define L3STR 65
#define L4STR 33

__global__ __launch_bounds__(256)
void ssim_tail_kernel(const float* __restrict__ X, const float* __restrict__ Y,
                      float* __restrict__ acc)
{
    __shared__ float2 t3[64 * L3STR];      // 33.3 KB
    __shared__ float2 p4[32 * L4STR];      // 8.4 KB
    __shared__ float red[4][4];

    const int bc  = blockIdx.x;
    const int tid = threadIdx.x;
    const size_t base = (size_t)bc * 64 * 64;

    for (int p = tid; p < 64 * 32; p += 256) {
        int r = p >> 5, c2 = p & 31;
        size_t g = base + (size_t)r * 64 + 2 * c2;
        float2 xv = *reinterpret_cast<const float2*>(X + g);
        float2 yv = *reinterpret_cast<const float2*>(Y + g);
        float2* dst = &t3[r * L3STR + 2 * c2];
        dst[0] = make_float2(xv.x, yv.x);
        dst[1] = make_float2(xv.y, yv.y);
    }
    __syncthreads();

    // L3: 54x54 outputs; 64 cols x 4 row-groups x 14 rows
    float s3 = 0.f, c3 = 0.f;
    {
        int tx = tid & 63, ty = tid >> 6, g0 = ty * 14;
        int txr = tx < 53 ? tx : 53;              // keep reads in-tile
        ssim_strip<14, L3STR>(t3, txr, g0, 63, 54 - g0, tx < 54, s3, c3);
    }

    // pool 64->32 in LDS (reads t3, writes p4: no hazard with L3 reads)
    for (int p = tid; p < 32 * 32; p += 256) {
        int r = p >> 5, c = p & 31;
        const float2* r0 = &t3[(2 * r)     * L3STR + 2 * c];
        const float2* r1 = &t3[(2 * r + 1) * L3STR + 2 * c];
        float2 a = r0[0], b = r0[1], cc = r1[0], d = r1[1];
        p4[r * L4STR + c] = make_float2(0.25f * (a.x + b.x + cc.x + d.x),
                                        0.25f * (a.y + b.y + cc.y + d.y));
    }
    __syncthreads();

    // L4: 22x22 outputs; 32 cols x 8 row-groups x 3 rows
    float s4 = 0.f, c4 = 0.f;
    {
        int tx = tid & 31, ty = tid >> 5, g0 = ty * 3;
        int txr = tx < 21 ? tx : 21;
        ssim_strip<3, L4STR>(p4, txr, g0, 31, 22 - g0, tx < 22, s4, c4);
    }

    // combined block reduction of {s3,c3,s4,c4}
#pragma unroll
    for (int off = 32; off; off >>= 1) {
        s3 += __shfl_down(s3, off); c3 += __shfl_down(c3, off);
        s4 += __shfl_down(s4, off); c4 += __shfl_down(c4, off);
    }
    if ((tid & 63) == 0) {
        int w = tid >> 6;
        red[0][w] = s3; red[1][w] = c3; red[2][w] = s4; red[3][w] = c4;
    }
    __syncthreads();
    if (tid == 0) {
        acc[3 * 96 + bc * 2 + 0] = red[0][0] + red[0][1] + red[0][2] + red[0][3];
        acc[3 * 96 + bc * 2 + 1] = red[1][0] + red[1][1] + red[1][2] + red[1][3];
        acc[4 * 96 + bc * 2 + 0] = red[2][0] + red[2][1] + red[2][2] + red[2][3];
        acc[4 * 96 + bc * 2 + 1] = red[3][0] + red[3][1] + red[3][2] + red[3][3];
    }
}

// Final: per (b,c) compute prod over levels of relu(mean)^w, mean over 48, 1 - result.
__launch_bounds__(64)
__global__ void finalize_kernel(const float* __restrict__ acc, float* __restrict__ out)
{
    const int lane = threadIdx.x;
    float prod = 0.f;
    if (lane < 48) {
        const float npix[5] = {252004.f, 60516.f, 13924.f, 2916.f, 484.f};
        const float wgt[5]  = {0.0448f, 0.2856f, 0.3001f, 0.2363f, 0.1333f};
        prod = 1.f;
#pragma unroll
        for (int l = 0; l < 5; ++l) {
            // levels 0..3 use cs mean, level 4 uses ssim mean
            float v = (l < 4) ? acc[l * 96 + lane * 2 + 1] : acc[l * 96 + lane * 2 + 0];
            v = v / npix[l];
            v = fmaxf(v, 0.f);
            prod *= powf(v, wgt[l]);
        }
    }
#pragma unroll
    for (int off = 32; off; off >>= 1) prod += __shfl_down(prod, off);
    if (lane == 0) out[0] = 1.f - prod / 48.f;
}

extern "C" void kernel_launch(void* const* d_in, const int* in_sizes, int n_in,
                              void* d_out, int out_size, void* d_ws, size_t ws_size,
                              hipStream_t stream)
{
    const float* gen = (const float*)d_in[0];
    const float* gt  = (const float*)d_in[1];
    float* out = (float*)d_out;

    char* ws = (char*)d_ws;
    float* acc = (float*)ws;                 // 5*48*2 floats = 1920 B
    float* p   = (float*)(ws + 2048);
    float* g1 = p; p += (size_t)48 * 256 * 256;
    float* t1 = p; p += (size_t)48 * 256 * 256;
    float* g2 = p; p += (size_t)48 * 128 * 128;
    float* t2 = p; p += (size_t)48 * 128 * 128;
    float* g3 = p; p += (size_t)48 * 64 * 64;
    float* t3 = p; p += (size_t)48 * 64 * 64;

    hipMemsetAsync(acc, 0, 5 * 48 * 2 * sizeof(float), stream);

    auto launch_ssim = [&](const float* X, const float* Y, int H, int lvl,
                           float* Xo, float* Yo) {
        int Hs = H - 10;
        dim3 grid((Hs + TW - 1) / TW, (Hs + TH - 1) / TH, 48);
        ssim_level_kernel<<<grid, 256, 0, stream>>>(X, Y, H, H, Hs, Hs,
                                                    acc + lvl * 96,
                                                    Xo, Yo, H / 2, 1);
    };

    launch_ssim(gen, gt, 512, 0, g1, t1);
    launch_ssim(g1, t1, 256, 1, g2, t2);
    launch_ssim(g2, t2, 128, 2, g3, t3);
    ssim_tail_kernel<<<48, 256, 0, stream>>>(g3, t3, acc);
    finalize_kernel<<<1, 64, 0, stream>>>(acc, out);
}